// Round 4
// baseline (471.187 us; speedup 1.0000x reference)
//
#include <hip/hip_runtime.h>
#include <math.h>

#define N 8192
#define D 512
#define KSEL 5
#define TEMP_INV 10.0f
#define MARGIN 0.012f
#define CCAP 48
#define APAD 40  // gemm LDS row pitch in shorts (verified conflict-free in R2/R3)

using short8 = __attribute__((ext_vector_type(8))) short;
using floatx4 = __attribute__((ext_vector_type(4))) float;

// Lexicographic top-5 insert: (value desc, index asc) — matches lax.top_k.
#define INS(TV, TIX, RI, VV, JJ)                                                     \
  {                                                                                  \
    const float _v = (VV);                                                           \
    const int _j = (JJ);                                                             \
    const bool _b4 = (_v > TV[RI][4]) || (_v == TV[RI][4] && _j < TIX[RI][4]);       \
    if (_b4) {                                                                       \
      const bool _b0 = (_v > TV[RI][0]) || (_v == TV[RI][0] && _j < TIX[RI][0]);     \
      const bool _b1 = (_v > TV[RI][1]) || (_v == TV[RI][1] && _j < TIX[RI][1]);     \
      const bool _b2 = (_v > TV[RI][2]) || (_v == TV[RI][2] && _j < TIX[RI][2]);     \
      const bool _b3 = (_v > TV[RI][3]) || (_v == TV[RI][3] && _j < TIX[RI][3]);     \
      TV[RI][4] = _b3 ? TV[RI][3] : _v;                                              \
      TIX[RI][4] = _b3 ? TIX[RI][3] : _j;                                            \
      TV[RI][3] = _b2 ? TV[RI][2] : (_b3 ? _v : TV[RI][3]);                          \
      TIX[RI][3] = _b2 ? TIX[RI][2] : (_b3 ? _j : TIX[RI][3]);                       \
      TV[RI][2] = _b1 ? TV[RI][1] : (_b2 ? _v : TV[RI][2]);                          \
      TIX[RI][2] = _b1 ? TIX[RI][1] : (_b2 ? _j : TIX[RI][2]);                       \
      TV[RI][1] = _b0 ? TV[RI][0] : (_b1 ? _v : TV[RI][1]);                          \
      TIX[RI][1] = _b0 ? TIX[RI][0] : (_b1 ? _j : TIX[RI][1]);                       \
      TV[RI][0] = _b0 ? _v : TV[RI][0];                                              \
      TIX[RI][0] = _b0 ? _j : TIX[RI][0];                                            \
    }                                                                                \
  }

__device__ inline unsigned short f2b(float f) {  // fp32 -> bf16 RNE
    unsigned int u = __float_as_uint(f);
    unsigned int r = (u + 0x7FFFu + ((u >> 16) & 1u)) >> 16;
    return (unsigned short)r;
}
__device__ inline float b2f(unsigned short u) {
    return __uint_as_float(((unsigned int)u) << 16);
}

// ---------------- Kernel 1: norms + bf16 normalized rows + zero ccount ---
__global__ __launch_bounds__(64) void prep_kernel(const float* __restrict__ X,
                                                  unsigned short* __restrict__ Xb,
                                                  float* __restrict__ inv,
                                                  int* __restrict__ ccount) {
    const int row = blockIdx.x;
    const int t = threadIdx.x;
    const float4* xr = (const float4*)(X + (size_t)row * D);
    const float4 a = xr[t];
    const float4 b = xr[t + 64];
    float ss = a.x * a.x + a.y * a.y + a.z * a.z + a.w * a.w +
               b.x * b.x + b.y * b.y + b.z * b.z + b.w * b.w;
#pragma unroll
    for (int off = 32; off > 0; off >>= 1) ss += __shfl_xor(ss, off, 64);
    const float iv = 1.0f / fmaxf(sqrtf(ss), 1e-12f);
    if (t == 0) {
        inv[row] = iv;
        ccount[row] = 0;
    }
    ushort4 ua, ub;
    ua.x = f2b(a.x * iv); ua.y = f2b(a.y * iv); ua.z = f2b(a.z * iv); ua.w = f2b(a.w * iv);
    ub.x = f2b(b.x * iv); ub.y = f2b(b.y * iv); ub.z = f2b(b.z * iv); ub.w = f2b(b.w * iv);
    ((ushort4*)(Xb + (size_t)row * D))[t] = ua;
    ((ushort4*)(Xb + (size_t)row * D))[t + 64] = ub;
}

// ---------------- Kernel 2: bf16 MFMA GEMM -> bf16 C in d_out ------------
__global__ __launch_bounds__(256) void gemm_kernel(const unsigned short* __restrict__ Xb,
                                                   unsigned short* __restrict__ Cout) {
    __shared__ unsigned short Al[128 * APAD];
    __shared__ unsigned short Bl[128 * APAD];
    const int tid = threadIdx.x;
    const int w = tid >> 6;
    const int lane = tid & 63;
    const int wr = w >> 1, wc = w & 1;
    const int i0 = blockIdx.y * 128, j0 = blockIdx.x * 128;

    const int r0 = tid >> 2;
    const int q = tid & 3;

    floatx4 acc[4][4];
#pragma unroll
    for (int ti = 0; ti < 4; ++ti)
#pragma unroll
        for (int tj = 0; tj < 4; ++tj) acc[ti][tj] = (floatx4){0.f, 0.f, 0.f, 0.f};

    const unsigned short* gA0 = Xb + (size_t)(i0 + r0) * D + q * 8;
    const unsigned short* gA1 = Xb + (size_t)(i0 + r0 + 64) * D + q * 8;
    const unsigned short* gB0 = Xb + (size_t)(j0 + r0) * D + q * 8;
    const unsigned short* gB1 = Xb + (size_t)(j0 + r0 + 64) * D + q * 8;

    int4 pa0 = *(const int4*)gA0;
    int4 pa1 = *(const int4*)gA1;
    int4 pb0 = *(const int4*)gB0;
    int4 pb1 = *(const int4*)gB1;

    const int lrow = lane & 15;
    const int lq = lane >> 4;
    const unsigned short* aF = Al + (size_t)(wr * 64 + lrow) * APAD + lq * 8;
    const unsigned short* bF = Bl + (size_t)(wc * 64 + lrow) * APAD + lq * 8;

    for (int kc = 0; kc < D / 32; ++kc) {
        __syncthreads();
        *(int4*)&Al[r0 * APAD + q * 8] = pa0;
        *(int4*)&Al[(r0 + 64) * APAD + q * 8] = pa1;
        *(int4*)&Bl[r0 * APAD + q * 8] = pb0;
        *(int4*)&Bl[(r0 + 64) * APAD + q * 8] = pb1;
        __syncthreads();
        if (kc < D / 32 - 1) {
            const int o = (kc + 1) * 32;
            pa0 = *(const int4*)(gA0 + o);
            pa1 = *(const int4*)(gA1 + o);
            pb0 = *(const int4*)(gB0 + o);
            pb1 = *(const int4*)(gB1 + o);
        }
        short8 af[4], bf[4];
#pragma unroll
        for (int ti = 0; ti < 4; ++ti) af[ti] = *(const short8*)(aF + ti * 16 * APAD);
#pragma unroll
        for (int tj = 0; tj < 4; ++tj) bf[tj] = *(const short8*)(bF + tj * 16 * APAD);
#pragma unroll
        for (int ti = 0; ti < 4; ++ti)
#pragma unroll
            for (int tj = 0; tj < 4; ++tj)
                acc[ti][tj] = __builtin_amdgcn_mfma_f32_16x16x32_bf16(af[ti], bf[tj],
                                                                      acc[ti][tj], 0, 0, 0);
    }

    // C/D: col = lane&15, row = (lane>>4)*4 + reg. (sim is symmetric, so a
    // row<->col swap would be harmless anyway.)
    const int orow0 = i0 + wr * 64 + lq * 4;
    const int ocol0 = j0 + wc * 64 + lrow;
#pragma unroll
    for (int ti = 0; ti < 4; ++ti)
#pragma unroll
        for (int tj = 0; tj < 4; ++tj)
#pragma unroll
            for (int reg = 0; reg < 4; ++reg)
                Cout[(size_t)(orow0 + ti * 16 + reg) * N + ocol0 + tj * 16] =
                    f2b(acc[ti][tj][reg]);
}

// ---------------- Kernel 3: scan C, emit candidates, zero output ---------
// Block b: 4 waves, wave w owns C row 4b+w (full 8192 cols). After both
// passes, the block zero-fills output f32 rows {2b, 2b+1} (they alias
// exactly C rows 4b..4b+3, all read by this block) and {4096+2b, 4096+2b+1}.
__global__ __launch_bounds__(256) void scan_kernel(const unsigned short* __restrict__ C,
                                                   float* __restrict__ outz,
                                                   int* __restrict__ ccount,
                                                   int* __restrict__ cidx) {
    const int tid = threadIdx.x;
    const int w = tid >> 6;
    const int lane = tid & 63;
    const int row = (int)blockIdx.x * 4 + w;
    const unsigned short* cr = C + (size_t)row * N;

    float tv[1][5];
    int tix[1][5];
#pragma unroll
    for (int s = 0; s < 5; ++s) { tv[0][s] = -1e30f; tix[0][s] = 0x7fffffff; }

    // pass 1: per-lane top-5 with max-prune fast path
    for (int it = 0; it < N / 256; ++it) {
        const ushort4 u = *(const ushort4*)(cr + it * 256 + lane * 4);
        const float v0 = b2f(u.x), v1 = b2f(u.y), v2 = b2f(u.z), v3 = b2f(u.w);
        const float vmax = fmaxf(fmaxf(v0, v1), fmaxf(v2, v3));
        if (vmax >= tv[0][4]) {  // >= keeps index-tie candidates
            const int jb = it * 256 + lane * 4;
            INS(tv, tix, 0, v0, jb);
            INS(tv, tix, 0, v1, jb + 1);
            INS(tv, tix, 0, v2, jb + 2);
            INS(tv, tix, 0, v3, jb + 3);
        }
    }
    // butterfly merge -> exact top-5 of approx values (all lanes converge)
#pragma unroll
    for (int m = 1; m < 64; m <<= 1) {
        float p0 = __shfl_xor(tv[0][0], m, 64), p1 = __shfl_xor(tv[0][1], m, 64);
        float p2 = __shfl_xor(tv[0][2], m, 64), p3 = __shfl_xor(tv[0][3], m, 64);
        float p4 = __shfl_xor(tv[0][4], m, 64);
        int q0 = __shfl_xor(tix[0][0], m, 64), q1 = __shfl_xor(tix[0][1], m, 64);
        int q2 = __shfl_xor(tix[0][2], m, 64), q3 = __shfl_xor(tix[0][3], m, 64);
        int q4 = __shfl_xor(tix[0][4], m, 64);
        INS(tv, tix, 0, p0, q0);
        INS(tv, tix, 0, p1, q1);
        INS(tv, tix, 0, p2, q2);
        INS(tv, tix, 0, p3, q3);
        INS(tv, tix, 0, p4, q4);
    }
    const float thr = tv[0][4] - MARGIN;

    // pass 2: emit all j with approx >= g5 - margin (superset of true top-5)
    for (int it = 0; it < N / 256; ++it) {
        const ushort4 u = *(const ushort4*)(cr + it * 256 + lane * 4);
        const int jb = it * 256 + lane * 4;
#pragma unroll
        for (int c = 0; c < 4; ++c) {
            const float v = b2f(c == 0 ? u.x : (c == 1 ? u.y : (c == 2 ? u.z : u.w)));
            if (v >= thr) {
                const int p = atomicAdd(&ccount[row], 1);
                if (p < CCAP) cidx[(size_t)row * CCAP + p] = jb + c;
            }
        }
    }

    __syncthreads();  // all C reads in this block done before zeroing

    // zero 4 output rows (128 KB): lower pair aliases this block's C rows
    const float4 z = make_float4(0.f, 0.f, 0.f, 0.f);
    const int rl = (int)blockIdx.x * 2;
#pragma unroll
    for (int rr = 0; rr < 2; ++rr) {
        float4* o0 = (float4*)(outz + (size_t)(rl + rr) * N);
        float4* o1 = (float4*)(outz + (size_t)(4096 + rl + rr) * N);
        for (int qy = tid; qy < N / 4; qy += 256) {
            o0[qy] = z;
            o1[qy] = z;
        }
    }
}

// ---------------- Kernel 4: fp32 rescore + exact top-5 + softmax + write -
__global__ __launch_bounds__(256) void finalize_kernel(const float* __restrict__ X,
                                                       const float* __restrict__ inv,
                                                       const int* __restrict__ ccount,
                                                       const int* __restrict__ cidx,
                                                       float* __restrict__ out) {
    const int tid = threadIdx.x;
    const int w = tid >> 6;
    const int lane = tid & 63;
    const int row = (int)blockIdx.x * 4 + w;

    const float4* xr = (const float4*)(X + (size_t)row * D);
    const float4 xa = xr[lane * 2];
    const float4 xb = xr[lane * 2 + 1];
    const float myinv = inv[row];
    int nc = ccount[row];
    if (nc > CCAP) nc = CCAP;

    float ev[1][5];
    int ei[1][5];
#pragma unroll
    for (int s = 0; s < 5; ++s) { ev[0][s] = -1e30f; ei[0][s] = 0x7fffffff; }

    for (int c = 0; c < nc; ++c) {
        const int cj = cidx[(size_t)row * CCAP + c];
        const float4* yr = (const float4*)(X + (size_t)cj * D);
        const float4 ya = yr[lane * 2];
        const float4 yb = yr[lane * 2 + 1];
        float p = xa.x * ya.x + xa.y * ya.y + xa.z * ya.z + xa.w * ya.w +
                  xb.x * yb.x + xb.y * yb.y + xb.z * yb.z + xb.w * yb.w;
#pragma unroll
        for (int off = 32; off > 0; off >>= 1) p += __shfl_xor(p, off, 64);
        const float val = p * myinv * inv[cj];
        INS(ev, ei, 0, val, cj);  // wave-uniform
    }

    if (lane == 0) {
        float e[KSEL];
        float sum = 0.f;
#pragma unroll
        for (int s = 0; s < KSEL; ++s) {
            e[s] = expf((ev[0][s] - ev[0][0]) * TEMP_INV);
            sum += e[s];
        }
        const float invs = 1.0f / sum;
#pragma unroll
        for (int s = 0; s < KSEL; ++s) {
            const int ix = ei[0][s];
            if (ix >= 0 && ix < N) out[(size_t)row * N + ix] = e[s] * invs;
        }
    }
}

extern "C" void kernel_launch(void* const* d_in, const int* in_sizes, int n_in,
                              void* d_out, int out_size, void* d_ws, size_t ws_size,
                              hipStream_t stream) {
    const float* X = (const float*)d_in[0];
    float* out = (float*)d_out;
    // ws: Xb bf16 [N*D = 8 MB] | inv [N f32] | ccount [N i32] | cidx [N*CCAP i32]
    unsigned short* Xb = (unsigned short*)d_ws;
    float* inv = (float*)(Xb + (size_t)N * D);
    int* ccount = (int*)(inv + N);
    int* cidx = ccount + N;

    hipLaunchKernelGGL(prep_kernel, dim3(N), dim3(64), 0, stream, X, Xb, inv, ccount);
    // d_out's first 128 MB doubles as the bf16 approx-sim matrix
    hipLaunchKernelGGL(gemm_kernel, dim3(N / 128, N / 128), dim3(256), 0, stream, Xb,
                       (unsigned short*)d_out);
    hipLaunchKernelGGL(scan_kernel, dim3(N / 4), dim3(256), 0, stream,
                       (const unsigned short*)d_out, (float*)d_out, ccount, cidx);
    hipLaunchKernelGGL(finalize_kernel, dim3(N / 4), dim3(256), 0, stream, X, inv, ccount,
                       cidx, out);
}